// Round 1
// baseline (6761.226 us; speedup 1.0000x reference)
//
#include <hip/hip_runtime.h>

#define HH 384
#define WW 1280

typedef unsigned short u16;
typedef unsigned int u32;

__device__ __forceinline__ float bf2f(u16 u){
  union { u32 i; float f; } v; v.i = ((u32)u) << 16; return v.f;
}
__device__ __forceinline__ u16 f2bf(float f){
  union { float f; u32 i; } v; v.f = f;
  u32 r = v.i + 0x7fffu + ((v.i >> 16) & 1u);
  return (u16)(r >> 16);
}

// Repack W1..W3 (OIHW f32) -> wf[layer][ic][tap][oc] f32 for uniform s_load in conv64.
__global__ __launch_bounds__(256) void prep_weights(const float* __restrict__ W1,
    const float* __restrict__ W2, const float* __restrict__ W3, float* __restrict__ wf){
  int idx = blockIdx.x * 256 + threadIdx.x;
  if (idx >= 3*64*9*64) return;
  int oc   = idx & 63;
  int tap  = (idx >> 6) % 9;
  int ic   = (idx / 576) & 63;
  int layer= idx / 36864;
  const float* Ws = (layer == 0) ? W1 : (layer == 1 ? W2 : W3);
  wf[idx] = Ws[(oc*64 + ic)*9 + tap];
}

// Layer 0: Cin=3 f32 -> 64ch bf16, tanh. One pixel x 64 oc per thread.
__global__ __launch_bounds__(256) void conv0_kernel(const float* __restrict__ img,
    const float* __restrict__ W0, const float* __restrict__ b0, u16* __restrict__ out){
  int x = blockIdx.x * 256 + threadIdx.x;
  int y = blockIdx.y;
  int n = blockIdx.z;
  const float* in = img + (size_t)n * 3 * HH * WW;
  float acc[64];
  #pragma unroll
  for (int o = 0; o < 64; ++o) acc[o] = b0[o];
  #pragma unroll
  for (int ic = 0; ic < 3; ++ic)
  #pragma unroll
  for (int dy = 0; dy < 3; ++dy) {
    int gy = y + dy - 1;
    #pragma unroll
    for (int dx = 0; dx < 3; ++dx) {
      int gx = x + dx - 1;
      float v = 0.f;
      if (gy >= 0 && gy < HH && (unsigned)gx < (unsigned)WW)
        v = in[((size_t)ic*HH + gy)*WW + gx];
      #pragma unroll
      for (int o = 0; o < 64; ++o)
        acc[o] = fmaf(v, W0[(o*3 + ic)*9 + dy*3 + dx], acc[o]);
    }
  }
  #pragma unroll
  for (int o = 0; o < 64; ++o)
    out[((size_t)(n*64 + o)*HH + y)*WW + x] = f2bf(tanhf(acc[o]));
}

// Layers 1-3: 64->64 direct conv. Block: 64x(x) * 4(y) tile, all 64 oc.
// Wave w owns oc [16w,16w+16) -> weight reads wave-uniform (s_load).
// LDS tile: [64 ic][6 rows][72 cols], col c <-> gx = x0 + c - 4.
template<bool TANH>
__global__ __launch_bounds__(256) void conv64_kernel(const u16* __restrict__ in,
    const float* __restrict__ wf, const float* __restrict__ bias, u16* __restrict__ out){
  __shared__ u16 tile[64*6*72];
  const int tid = threadIdx.x;
  const int x0 = blockIdx.x * 64;
  const int y0 = blockIdx.y * 4;
  const int n  = blockIdx.z;
  const u16* inN = in + (size_t)n * 64 * HH * WW;

  // stage center: cols 4..67 <-> gx = x0..x0+63 (always in-bounds in x)
  for (int e = tid; e < 64*6*16; e += 256) {
    int chunk = e & 15;
    int row   = (e >> 4) % 6;
    int ic    = e / 96;
    int gy = y0 - 1 + row;
    ushort4 v = make_ushort4(0,0,0,0);
    if (gy >= 0 && gy < HH)
      v = *(const ushort4*)(inN + ((size_t)ic*HH + gy)*WW + x0 + chunk*4);
    *(ushort4*)&tile[(ic*6 + row)*72 + 4 + chunk*4] = v;
  }
  // halo: col 3 (gx=x0-1) and col 68 (gx=x0+64)
  for (int e = tid; e < 64*6*2; e += 256) {
    int side = e & 1;
    int row  = (e >> 1) % 6;
    int ic   = e / 12;
    int gy = y0 - 1 + row;
    int gx = side ? x0 + 64 : x0 - 1;
    u16 v = 0;
    if (gy >= 0 && gy < HH && gx >= 0 && gx < WW)
      v = inN[((size_t)ic*HH + gy)*WW + gx];
    tile[(ic*6 + row)*72 + (side ? 68 : 3)] = v;
  }
  __syncthreads();

  const int wv   = __builtin_amdgcn_readfirstlane(tid >> 6); // wave id, SGPR
  const int lane = tid & 63;
  const int xq   = lane & 15;   // 4 consecutive x per thread
  const int yy   = lane >> 4;   // row within tile
  const int ocb  = wv * 16;

  float acc[16][4];
  #pragma unroll
  for (int o = 0; o < 16; ++o) {
    float b = bias[ocb + o];
    #pragma unroll
    for (int j = 0; j < 4; ++j) acc[o][j] = b;
  }

  #pragma unroll 1
  for (int ic = 0; ic < 64; ++ic) {
    #pragma unroll
    for (int dy = 0; dy < 3; ++dy) {
      const u16* trow = &tile[(ic*6 + yy + dy)*72 + xq*4];
      ushort4 r0 = *(const ushort4*)(trow);
      ushort4 r1 = *(const ushort4*)(trow + 4);
      ushort4 r2 = *(const ushort4*)(trow + 8);
      // iv[t] <-> col xq*4 + 3 + t, need t = dx + j in [0,5]
      float iv[6];
      iv[0] = bf2f(r0.w);
      iv[1] = bf2f(r1.x); iv[2] = bf2f(r1.y); iv[3] = bf2f(r1.z); iv[4] = bf2f(r1.w);
      iv[5] = bf2f(r2.x);
      const float* wrow = &wf[(ic*9 + dy*3)*64 + ocb];
      #pragma unroll
      for (int dx = 0; dx < 3; ++dx) {
        #pragma unroll
        for (int o = 0; o < 16; ++o) {
          float w = wrow[dx*64 + o];   // wave-uniform -> SGPR
          #pragma unroll
          for (int j = 0; j < 4; ++j)
            acc[o][j] = fmaf(iv[dx + j], w, acc[o][j]);
        }
      }
    }
  }

  const int oy = y0 + yy;
  const int ox = x0 + xq*4;
  #pragma unroll
  for (int o = 0; o < 16; ++o) {
    float v0 = acc[o][0], v1 = acc[o][1], v2 = acc[o][2], v3 = acc[o][3];
    if (TANH) { v0 = tanhf(v0); v1 = tanhf(v1); v2 = tanhf(v2); v3 = tanhf(v3); }
    ushort4 pv = make_ushort4(f2bf(v0), f2bf(v1), f2bf(v2), f2bf(v3));
    *(ushort4*)&out[((size_t)(n*64 + ocb + o)*HH + oy)*WW + ox] = pv;
  }
}

// Correlation: corr[b,d,y,x] = sum_c L[b,c,y,x] * R[b,c,y,x-d], zero pad left.
// Block: (b, y, 64-x tile). LDS: Lt[64c][64x], Rt[64c][192j], j <-> gx = x0-128+j.
__global__ __launch_bounds__(256) void corr_kernel(const u16* __restrict__ phiL,
    const u16* __restrict__ phiR, float* __restrict__ out){
  __shared__ u16 Lt[64*64];
  __shared__ u16 Rt[64*192];
  const int tid = threadIdx.x;
  const int x0 = blockIdx.x * 64;
  const int y  = blockIdx.y;
  const int b  = blockIdx.z;
  const u16* L = phiL + (size_t)b * 64 * HH * WW;
  const u16* R = phiR + (size_t)b * 64 * HH * WW;

  for (int e = tid; e < 64*16; e += 256) {
    int c = e >> 4, q = e & 15;
    *(ushort4*)&Lt[c*64 + q*4] = *(const ushort4*)(L + ((size_t)c*HH + y)*WW + x0 + q*4);
  }
  for (int e = tid; e < 64*48; e += 256) {
    int c = e / 48, q = e % 48;
    int gx = x0 - 128 + q*4;
    ushort4 v = make_ushort4(0,0,0,0);
    if (gx >= 0) v = *(const ushort4*)(R + ((size_t)c*HH + y)*WW + gx);
    *(ushort4*)&Rt[c*192 + q*4] = v;
  }
  __syncthreads();

  const int xq = tid & 15;       // 4 x per thread
  const int dg = tid >> 4;       // 8 d per thread
  const int d0 = dg * 8;
  float acc[8][4];
  #pragma unroll
  for (int i = 0; i < 8; ++i)
    #pragma unroll
    for (int j = 0; j < 4; ++j) acc[i][j] = 0.f;

  const int jb = xq*4 - d0 + 128;
  #pragma unroll 4
  for (int c = 0; c < 64; ++c) {
    ushort4 l4 = *(const ushort4*)&Lt[c*64 + xq*4];
    float lv[4] = { bf2f(l4.x), bf2f(l4.y), bf2f(l4.z), bf2f(l4.w) };
    const u16* rp = &Rt[c*192 + jb - 8];
    ushort4 q0 = *(const ushort4*)(rp);
    ushort4 q1 = *(const ushort4*)(rp + 4);
    ushort4 q2 = *(const ushort4*)(rp + 8);
    float rv[12] = { bf2f(q0.x), bf2f(q0.y), bf2f(q0.z), bf2f(q0.w),
                     bf2f(q1.x), bf2f(q1.y), bf2f(q1.z), bf2f(q1.w),
                     bf2f(q2.x), bf2f(q2.y), bf2f(q2.z), bf2f(q2.w) };
    #pragma unroll
    for (int dj = 0; dj < 8; ++dj)
      #pragma unroll
      for (int xi = 0; xi < 4; ++xi)
        acc[dj][xi] = fmaf(lv[xi], rv[8 + xi - dj], acc[dj][xi]);
  }

  #pragma unroll
  for (int dj = 0; dj < 8; ++dj) {
    float4 v = make_float4(acc[dj][0], acc[dj][1], acc[dj][2], acc[dj][3]);
    *(float4*)&out[((size_t)(b*128 + d0 + dj)*HH + y)*WW + x0 + xq*4] = v;
  }
}

extern "C" void kernel_launch(void* const* d_in, const int* in_sizes, int n_in,
                              void* d_out, int out_size, void* d_ws, size_t ws_size,
                              hipStream_t stream){
  const float* l  = (const float*)d_in[0];
  const float* r  = (const float*)d_in[1];
  const float* W0 = (const float*)d_in[2];
  const float* b0 = (const float*)d_in[3];
  const float* W1 = (const float*)d_in[4];
  const float* b1 = (const float*)d_in[5];
  const float* W2 = (const float*)d_in[6];
  const float* b2 = (const float*)d_in[7];
  const float* W3 = (const float*)d_in[8];
  const float* b3 = (const float*)d_in[9];
  float* out = (float*)d_out;

  const size_t SIDE = (size_t)2 * 64 * HH * WW;      // elements per side's features
  float* wf = (float*)d_ws;                          // 3*64*9*64 f32 = 432 KB
  u16* BL = (u16*)((char*)d_ws + (4u << 20));        // phiL (bf16)
  u16* BR = BL + SIDE;                               // phiR (bf16)
  u16* A  = (u16*)d_out;                             // ping scratch inside d_out
                                                     // (fully overwritten by corr)
  prep_weights<<<dim3(432), dim3(256), 0, stream>>>(W1, W2, W3, wf);

  for (int s = 0; s < 2; ++s) {
    const float* img = s ? r : l;
    u16* B = s ? BR : BL;
    conv0_kernel<<<dim3(WW/256, HH, 2), dim3(256), 0, stream>>>(img, W0, b0, A);
    conv64_kernel<true ><<<dim3(WW/64, HH/4, 2), dim3(256), 0, stream>>>(A, wf + 0*36864, b1, B);
    conv64_kernel<true ><<<dim3(WW/64, HH/4, 2), dim3(256), 0, stream>>>(B, wf + 1*36864, b2, A);
    conv64_kernel<false><<<dim3(WW/64, HH/4, 2), dim3(256), 0, stream>>>(A, wf + 2*36864, b3, B);
  }

  corr_kernel<<<dim3(WW/64, HH, 2), dim3(256), 0, stream>>>(BL, BR, out);
}

// Round 2
// 1405.541 us; speedup vs baseline: 4.8104x; 4.8104x over previous
//
#include <hip/hip_runtime.h>

#define HH 384
#define WW 1280

typedef unsigned short u16;
typedef unsigned int u32;
typedef __attribute__((ext_vector_type(8))) short short8;
typedef __attribute__((ext_vector_type(8))) unsigned short u16x8;
typedef __attribute__((ext_vector_type(4))) float f32x4;

__device__ __forceinline__ float bf2f(u16 u){ union{u32 i;float f;}v; v.i=((u32)u)<<16; return v.f; }
__device__ __forceinline__ u16 f2bf(float f){ union{float f;u32 i;}v; v.f=f; u32 r=v.i+0x7fffu+((v.i>>16)&1u); return (u16)(r>>16); }
__device__ __forceinline__ float ftanh(float x){
  float e = __expf(2.0f*x);
  return 1.0f - 2.0f/(e+1.0f);
}
__device__ __forceinline__ void gload_lds16(const void* g, void* l){
  __builtin_amdgcn_global_load_lds((const __attribute__((address_space(1))) void*)g,
                                   (__attribute__((address_space(3))) void*)l, 16, 0, 0);
}

// Repack W1..W3 (OIHW f32) -> wf[layer][tap][oc][ic'] bf16, with the LDS read
// swizzle (byte ^= (oc&7)<<4) pre-inverted so linear global_load_lds staging
// lands the swizzled image: ic' = ic ^ ((oc&7)<<3).
__global__ __launch_bounds__(256) void prep_weights(const float* __restrict__ W1,
    const float* __restrict__ W2, const float* __restrict__ W3, u16* __restrict__ wf){
  int idx = blockIdx.x*256 + threadIdx.x;          // 3*9*64*64 = 110592
  if (idx >= 110592) return;
  int m    = idx & 63;
  int oc   = (idx>>6) & 63;
  int tap  = (idx>>12) % 9;
  int layer= idx / 36864;
  int ic   = m ^ ((oc&7)<<3);
  const float* Ws = layer==0 ? W1 : (layer==1 ? W2 : W3);
  wf[idx] = f2bf(Ws[(oc*64+ic)*9 + tap]);
}

// Layer 0: 3ch f32 NCHW -> 64ch bf16 NHWC, tanh. One pixel x 64 oc per thread.
__global__ __launch_bounds__(256) void conv0_kernel(const float* __restrict__ img,
    const float* __restrict__ W0, const float* __restrict__ b0, u16* __restrict__ out){
  int x = blockIdx.x*256 + threadIdx.x;
  int y = blockIdx.y;
  int n = blockIdx.z;
  const float* in = img + (size_t)n*3*HH*WW;
  float acc[64];
  #pragma unroll
  for (int o=0;o<64;++o) acc[o] = b0[o];
  #pragma unroll
  for (int ic=0; ic<3; ++ic)
  #pragma unroll
  for (int dy=0; dy<3; ++dy){
    int gy = y + dy - 1;
    #pragma unroll
    for (int dx=0; dx<3; ++dx){
      int gx = x + dx - 1;
      float v = 0.f;
      if (gy>=0 && gy<HH && (unsigned)gx < (unsigned)WW)
        v = in[((size_t)ic*HH + gy)*WW + gx];
      #pragma unroll
      for (int o=0;o<64;++o)
        acc[o] = fmaf(v, W0[(o*3+ic)*9 + dy*3 + dx], acc[o]);
    }
  }
  u16* op = out + ((size_t)((n*HH + y)*WW) + x)*64;
  #pragma unroll
  for (int cc=0; cc<8; ++cc){
    u16x8 v;
    #pragma unroll
    for (int k=0;k<8;++k) v[k] = f2bf(ftanh(acc[cc*8+k]));
    *(u16x8*)(op + cc*8) = v;
  }
}

// Layers 1-3: 64->64 conv as 9 shifted MFMA GEMMs. NHWC bf16 in/out.
// Block: 256 px (64x * 4y) x 64 oc; wave w owns y-row y0+w, M=64 N=64 (4x4 frags).
// Input LDS [6 rows][66 cols][64 ic], element (r,c,ic) at byte
//   (r*66+c)*128 + ((ic*2) ^ ((c&7)<<4))  -- staged linearly from pre-swizzled src.
// Weight LDS per tap [64 oc][64 ic], (oc,ic) at byte oc*128 + ((ic*2)^((oc&7)<<4)).
template<bool TANH>
__global__ __launch_bounds__(256) void conv64_kernel(const u16* __restrict__ in,
    const u16* __restrict__ wfL, const float* __restrict__ bias,
    const u16* __restrict__ zpad, u16* __restrict__ out){
  __shared__ u16 tile[6*66*64];      // 50688 B
  __shared__ u16 wbuf[2][4096];      // 2 x 8192 B
  const int tid = threadIdx.x;
  const int x0 = blockIdx.x*64;
  const int y0 = blockIdx.y*4;
  const int n  = blockIdx.z;
  const u16* inN = in + (size_t)n*HH*WW*64;

  // stage input tile: 3168 16B-chunks, chunk q = (row*66+col)*8 + j
  for (int q0 = 0; q0 < 3168; q0 += 256){
    int q = q0 + tid;
    if (q < 3168){
      int row = q / 528;
      int rem = q - row*528;
      int col = rem >> 3;
      int j   = rem & 7;
      int gy = y0 - 1 + row;
      int gx = x0 - 1 + col;
      const u16* g;
      if ((unsigned)gy < (unsigned)HH && (unsigned)gx < (unsigned)WW)
        g = inN + (((size_t)(gy*WW + gx))<<6) + ((j ^ (col&7))<<3);
      else
        g = zpad + (j<<3);
      gload_lds16(g, &tile[(size_t)(q & ~63)*8]);
    }
  }
  // stage weights tap 0 -> wbuf[0] (512 chunks)
  #pragma unroll
  for (int c=0;c<2;++c){
    int q = c*256 + tid;
    gload_lds16(wfL + (size_t)q*8, &wbuf[0][(q & ~63)*8]);
  }
  __syncthreads();

  const int lane = tid & 63;
  const int wv = tid >> 6;
  const int l15 = lane & 15;
  const int lh  = lane >> 4;

  f32x4 acc[4][4];
  #pragma unroll
  for (int mt=0;mt<4;++mt)
    #pragma unroll
    for (int nt=0;nt<4;++nt) acc[mt][nt] = (f32x4){0.f,0.f,0.f,0.f};

  #pragma unroll
  for (int tap = 0; tap < 9; ++tap){
    const int dy = tap/3, dx = tap%3;
    if (tap < 8){
      const u16* wsrc = wfL + (size_t)(tap+1)*4096;
      u16* wdst = wbuf[(tap+1)&1];
      #pragma unroll
      for (int c=0;c<2;++c){
        int q = c*256 + tid;
        gload_lds16(wsrc + (size_t)q*8, &wdst[(q & ~63)*8]);
      }
    }
    const char* wb = (const char*)wbuf[tap&1];
    const char* tb = (const char*)tile;
    const int xorA = ((l15 + dx)&7)<<4;
    const int xorB = (l15&7)<<4;
    #pragma unroll
    for (int kh=0; kh<2; ++kh){
      const int kbyte = kh*64 + lh*16;
      short8 a[4], b[4];
      #pragma unroll
      for (int mt=0; mt<4; ++mt){
        int col = mt*16 + l15 + dx;
        a[mt] = *(const short8*)(tb + ((wv+dy)*66 + col)*128 + (kbyte ^ xorA));
      }
      #pragma unroll
      for (int nt=0; nt<4; ++nt){
        int oc = nt*16 + l15;
        b[nt] = *(const short8*)(wb + oc*128 + (kbyte ^ xorB));
      }
      #pragma unroll
      for (int mt=0; mt<4; ++mt)
        #pragma unroll
        for (int nt=0; nt<4; ++nt)
          acc[mt][nt] = __builtin_amdgcn_mfma_f32_16x16x32_bf16(a[mt], b[nt], acc[mt][nt], 0,0,0);
    }
    __syncthreads();
  }

  float bv[4];
  #pragma unroll
  for (int nt=0;nt<4;++nt) bv[nt] = bias[nt*16 + l15];
  const int gy = y0 + wv;
  u16* outR = out + (size_t)n*HH*WW*64 + (size_t)gy*WW*64;
  #pragma unroll
  for (int mt=0; mt<4; ++mt){
    #pragma unroll
    for (int r=0; r<4; ++r){
      int x = x0 + mt*16 + lh*4 + r;
      u16* op = outR + (size_t)x*64 + l15;
      #pragma unroll
      for (int nt=0; nt<4; ++nt){
        float v = acc[mt][nt][r] + bv[nt];
        if (TANH) v = ftanh(v);
        op[nt*16] = f2bf(v);
      }
    }
  }
}

// Correlation over NHWC bf16 features: corr[b,d,y,x] = sum_c L[y,x,c]*R[y,x-d,c].
__global__ __launch_bounds__(256) void corr_kernel(const u16* __restrict__ phiL,
    const u16* __restrict__ phiR, float* __restrict__ out){
  __shared__ u16 Lt[64*64];     // x*128B, swizzled by (x&7)<<4
  __shared__ u16 Rt[192*64];    // j <-> gx = x0-128+j
  const int tid = threadIdx.x;
  const int x0 = blockIdx.x*64;
  const int y  = blockIdx.y;
  const int b  = blockIdx.z;
  const u16* Lb = phiL + (size_t)b*HH*WW*64;
  const u16* Rb = phiR + (size_t)b*HH*WW*64;

  #pragma unroll
  for (int c0=0;c0<2;++c0){
    int q = c0*256 + tid;             // 512 chunks
    int x = q>>3, cc = q&7;
    u16x8 v = *(const u16x8*)(Lb + (((size_t)(y*WW + x0 + x))<<6) + (cc<<3));
    *(u16x8*)((char*)Lt + x*128 + ((cc*16) ^ ((x&7)<<4))) = v;
  }
  #pragma unroll
  for (int c0=0;c0<6;++c0){
    int q = c0*256 + tid;             // 1536 chunks
    int xj = q>>3, cc = q&7;
    int gx = x0 - 128 + xj;
    u16x8 v = (u16x8){0,0,0,0,0,0,0,0};
    if (gx >= 0) v = *(const u16x8*)(Rb + (((size_t)(y*WW + gx))<<6) + (cc<<3));
    *(u16x8*)((char*)Rt + xj*128 + ((cc*16) ^ ((xj&7)<<4))) = v;
  }
  __syncthreads();

  const int xq = tid & 15;
  const int dg = tid >> 4;
  const int d0 = dg*8;
  const int jb = xq*4 - d0 + 128;
  float acc[8][4];
  #pragma unroll
  for (int i=0;i<8;++i)
    #pragma unroll
    for (int j=0;j<4;++j) acc[i][j] = 0.f;

  for (int cc=0; cc<8; ++cc){
    u16x8 lv[4], rv[12];
    #pragma unroll
    for (int xi=0; xi<4; ++xi){
      int x = xq*4 + xi;
      lv[xi] = *(const u16x8*)((const char*)Lt + x*128 + ((cc*16) ^ ((x&7)<<4)));
    }
    #pragma unroll
    for (int t=0; t<12; ++t){
      int j = jb - 8 + t;
      rv[t] = *(const u16x8*)((const char*)Rt + j*128 + ((cc*16) ^ ((j&7)<<4)));
    }
    #pragma unroll
    for (int c=0; c<8; ++c){
      float l4[4], r12[12];
      #pragma unroll
      for (int xi=0;xi<4;++xi) l4[xi] = bf2f(lv[xi][c]);
      #pragma unroll
      for (int t=0;t<12;++t)   r12[t] = bf2f(rv[t][c]);
      #pragma unroll
      for (int dj=0;dj<8;++dj)
        #pragma unroll
        for (int xi=0;xi<4;++xi)
          acc[dj][xi] = fmaf(l4[xi], r12[8+xi-dj], acc[dj][xi]);
    }
  }

  #pragma unroll
  for (int dj=0;dj<8;++dj){
    float4 v = make_float4(acc[dj][0], acc[dj][1], acc[dj][2], acc[dj][3]);
    *(float4*)&out[((size_t)(b*128 + d0 + dj)*HH + y)*WW + x0 + xq*4] = v;
  }
}

extern "C" void kernel_launch(void* const* d_in, const int* in_sizes, int n_in,
                              void* d_out, int out_size, void* d_ws, size_t ws_size,
                              hipStream_t stream){
  const float* l  = (const float*)d_in[0];
  const float* r  = (const float*)d_in[1];
  const float* W0 = (const float*)d_in[2];
  const float* b0 = (const float*)d_in[3];
  const float* W1 = (const float*)d_in[4];
  const float* b1 = (const float*)d_in[5];
  const float* W2 = (const float*)d_in[6];
  const float* b2 = (const float*)d_in[7];
  const float* W3 = (const float*)d_in[8];
  const float* b3 = (const float*)d_in[9];
  float* out = (float*)d_out;

  const size_t SIDE = (size_t)2*HH*WW*64;            // elements per side (NHWC bf16)
  u16* wf   = (u16*)d_ws;                            // 110592 u16
  u16* zpad = (u16*)((char*)d_ws + (1u<<20));        // 256 B zeros
  u16* BL   = (u16*)((char*)d_ws + (2u<<20));
  u16* BR   = BL + SIDE;
  u16* A    = (u16*)d_out;                           // ping scratch inside d_out

  hipMemsetAsync(zpad, 0, 256, stream);
  prep_weights<<<dim3(432), dim3(256), 0, stream>>>(W1, W2, W3, wf);

  for (int s = 0; s < 2; ++s){
    const float* img = s ? r : l;
    u16* B = s ? BR : BL;
    conv0_kernel<<<dim3(WW/256, HH, 2), dim3(256), 0, stream>>>(img, W0, b0, A);
    conv64_kernel<true ><<<dim3(WW/64, HH/4, 2), dim3(256), 0, stream>>>(A, wf + 0*36864, b1, zpad, B);
    conv64_kernel<true ><<<dim3(WW/64, HH/4, 2), dim3(256), 0, stream>>>(B, wf + 1*36864, b2, zpad, A);
    conv64_kernel<false><<<dim3(WW/64, HH/4, 2), dim3(256), 0, stream>>>(A, wf + 2*36864, b3, zpad, B);
  }

  corr_kernel<<<dim3(WW/64, HH, 2), dim3(256), 0, stream>>>(BL, BR, out);
}

// Round 4
// 1076.821 us; speedup vs baseline: 6.2789x; 1.3053x over previous
//
#include <hip/hip_runtime.h>

#define HH 384
#define WW 1280

typedef unsigned short u16;
typedef unsigned int u32;
typedef __attribute__((ext_vector_type(8))) short short8;
typedef __attribute__((ext_vector_type(8))) unsigned short u16x8;
typedef __attribute__((ext_vector_type(4))) float f32x4;

__device__ __forceinline__ float bf2f(u16 u){ union{u32 i;float f;}v; v.i=((u32)u)<<16; return v.f; }
__device__ __forceinline__ u16 f2bf(float f){ union{float f;u32 i;}v; v.f=f; u32 r=v.i+0x7fffu+((v.i>>16)&1u); return (u16)(r>>16); }
__device__ __forceinline__ float ftanh(float x){
  float e = __expf(2.0f*x);
  return 1.0f - 2.0f/(e+1.0f);
}
__device__ __forceinline__ void gload_lds16(const void* g, void* l){
  __builtin_amdgcn_global_load_lds((const __attribute__((address_space(1))) void*)g,
                                   (__attribute__((address_space(3))) void*)l, 16, 0, 0);
}

// Repack W1..W3 (OIHW f32) -> wf[layer][tap][oc][ic'] bf16, with the LDS read
// swizzle (byte ^= (oc&7)<<4) pre-inverted so linear global_load_lds staging
// lands the swizzled image: ic' = ic ^ ((oc&7)<<3).
__global__ __launch_bounds__(256) void prep_weights(const float* __restrict__ W1,
    const float* __restrict__ W2, const float* __restrict__ W3, u16* __restrict__ wf){
  int idx = blockIdx.x*256 + threadIdx.x;          // 3*9*64*64 = 110592
  if (idx >= 110592) return;
  int m    = idx & 63;
  int oc   = (idx>>6) & 63;
  int tap  = (idx>>12) % 9;
  int layer= idx / 36864;
  int ic   = m ^ ((oc&7)<<3);
  const float* Ws = layer==0 ? W1 : (layer==1 ? W2 : W3);
  wf[idx] = f2bf(Ws[(oc*64+ic)*9 + tap]);
}

// Layer 0: 3ch f32 NCHW -> 64ch bf16 NHWC, tanh. One pixel x 64 oc per thread.
__global__ __launch_bounds__(256) void conv0_kernel(const float* __restrict__ img,
    const float* __restrict__ W0, const float* __restrict__ b0, u16* __restrict__ out){
  int x = blockIdx.x*256 + threadIdx.x;
  int y = blockIdx.y;
  int n = blockIdx.z;
  const float* in = img + (size_t)n*3*HH*WW;
  float acc[64];
  #pragma unroll
  for (int o=0;o<64;++o) acc[o] = b0[o];
  #pragma unroll
  for (int ic=0; ic<3; ++ic)
  #pragma unroll
  for (int dy=0; dy<3; ++dy){
    int gy = y + dy - 1;
    #pragma unroll
    for (int dx=0; dx<3; ++dx){
      int gx = x + dx - 1;
      float v = 0.f;
      if (gy>=0 && gy<HH && (unsigned)gx < (unsigned)WW)
        v = in[((size_t)ic*HH + gy)*WW + gx];
      #pragma unroll
      for (int o=0;o<64;++o)
        acc[o] = fmaf(v, W0[(o*3+ic)*9 + dy*3 + dx], acc[o]);
    }
  }
  u16* op = out + ((size_t)((n*HH + y)*WW) + x)*64;
  #pragma unroll
  for (int cc=0; cc<8; ++cc){
    u16x8 v;
    #pragma unroll
    for (int k=0;k<8;++k) v[k] = f2bf(ftanh(acc[cc*8+k]));
    *(u16x8*)(op + cc*8) = v;
  }
}

// Layers 1-3: 64->64 conv as 9 shifted MFMA GEMMs. NHWC bf16 in/out.
// Block: 256 px (64x * 4y) x 64 oc; wave w owns y-row y0+w, M=64 N=64 (4x4 frags).
// Input LDS [6 rows][66 cols][64 ic], element (r,c,ic) at byte
//   (r*66+c)*128 + ((ic*2) ^ ((c&7)<<4))  -- staged linearly from pre-swizzled src.
// Weight LDS per tap [64 oc][64 ic], (oc,ic) at byte oc*128 + ((ic*2)^((oc&7)<<4)).
template<bool TANH>
__global__ __launch_bounds__(256) void conv64_kernel(const u16* __restrict__ in,
    const u16* __restrict__ wfL, const float* __restrict__ bias,
    const u16* __restrict__ zpad, u16* __restrict__ out){
  __shared__ u16 tile[6*66*64];      // 50688 B
  __shared__ u16 wbuf[2][4096];      // 2 x 8192 B
  const int tid = threadIdx.x;
  const int x0 = blockIdx.x*64;
  const int y0 = blockIdx.y*4;
  const int n  = blockIdx.z;
  const u16* inN = in + (size_t)n*HH*WW*64;

  // stage input tile: 3168 16B-chunks, chunk q = (row*66+col)*8 + j
  for (int q0 = 0; q0 < 3168; q0 += 256){
    int q = q0 + tid;
    if (q < 3168){
      int row = q / 528;
      int rem = q - row*528;
      int col = rem >> 3;
      int j   = rem & 7;
      int gy = y0 - 1 + row;
      int gx = x0 - 1 + col;
      const u16* g;
      if ((unsigned)gy < (unsigned)HH && (unsigned)gx < (unsigned)WW)
        g = inN + (((size_t)(gy*WW + gx))<<6) + ((j ^ (col&7))<<3);
      else
        g = zpad + (j<<3);
      gload_lds16(g, &tile[(size_t)(q & ~63)*8]);
    }
  }
  // stage weights tap 0 -> wbuf[0] (512 chunks)
  #pragma unroll
  for (int c=0;c<2;++c){
    int q = c*256 + tid;
    gload_lds16(wfL + (size_t)q*8, &wbuf[0][(q & ~63)*8]);
  }
  __syncthreads();

  const int lane = tid & 63;
  const int wv = tid >> 6;
  const int l15 = lane & 15;
  const int lh  = lane >> 4;

  f32x4 acc[4][4];
  #pragma unroll
  for (int mt=0;mt<4;++mt)
    #pragma unroll
    for (int nt=0;nt<4;++nt) acc[mt][nt] = (f32x4){0.f,0.f,0.f,0.f};

  #pragma unroll
  for (int tap = 0; tap < 9; ++tap){
    const int dy = tap/3, dx = tap%3;
    if (tap < 8){
      const u16* wsrc = wfL + (size_t)(tap+1)*4096;
      u16* wdst = wbuf[(tap+1)&1];
      #pragma unroll
      for (int c=0;c<2;++c){
        int q = c*256 + tid;
        gload_lds16(wsrc + (size_t)q*8, &wdst[(q & ~63)*8]);
      }
    }
    const char* wb = (const char*)wbuf[tap&1];
    const char* tb = (const char*)tile;
    const int xorA = ((l15 + dx)&7)<<4;
    const int xorB = (l15&7)<<4;
    #pragma unroll
    for (int kh=0; kh<2; ++kh){
      const int kbyte = kh*64 + lh*16;
      short8 a[4], b[4];
      #pragma unroll
      for (int mt=0; mt<4; ++mt){
        int col = mt*16 + l15 + dx;
        a[mt] = *(const short8*)(tb + ((wv+dy)*66 + col)*128 + (kbyte ^ xorA));
      }
      #pragma unroll
      for (int nt=0; nt<4; ++nt){
        int oc = nt*16 + l15;
        b[nt] = *(const short8*)(wb + oc*128 + (kbyte ^ xorB));
      }
      #pragma unroll
      for (int mt=0; mt<4; ++mt)
        #pragma unroll
        for (int nt=0; nt<4; ++nt)
          acc[mt][nt] = __builtin_amdgcn_mfma_f32_16x16x32_bf16(a[mt], b[nt], acc[mt][nt], 0,0,0);
    }
    __syncthreads();
  }

  float bv[4];
  #pragma unroll
  for (int nt=0;nt<4;++nt) bv[nt] = bias[nt*16 + l15];
  const int gy = y0 + wv;
  u16* outR = out + (size_t)n*HH*WW*64 + (size_t)gy*WW*64;
  #pragma unroll
  for (int mt=0; mt<4; ++mt){
    #pragma unroll
    for (int r=0; r<4; ++r){
      int x = x0 + mt*16 + lh*4 + r;
      u16* op = outR + (size_t)x*64 + l15;
      #pragma unroll
      for (int nt=0; nt<4; ++nt){
        float v = acc[mt][nt][r] + bv[nt];
        if (TANH) v = ftanh(v);
        op[nt*16] = f2bf(v);
      }
    }
  }
}

// Correlation via banded MFMA GEMM. Per block (b, y, 64-x tile):
//   G[x, j] = sum_c L[x,c] * R[j,c],  j window = [x0-128, x0+64)  (192 cols)
//   corr[d, x] = G[x, x-d] for d in [0,128)
// LDS: Lt 64x128B + Rt 192x128B (32 KB, swizzled like conv64), then reused as
// band[128][65] f32 (33 KB) for the diagonal->row transpose before store.
__global__ __launch_bounds__(256) void corr_kernel(const u16* __restrict__ phiL,
    const u16* __restrict__ phiR, const u16* __restrict__ zpad, float* __restrict__ out){
  __shared__ char lds[33280];
  u16* Lt = (u16*)lds;             // 8192 B
  u16* Rt = (u16*)(lds + 8192);    // 24576 B
  float* band = (float*)lds;       // 128*65 f32 = 33280 B
  const int tid = threadIdx.x;
  const int x0 = blockIdx.x*64;
  const int y  = blockIdx.y;
  const int b  = blockIdx.z;
  const u16* Lrow = phiL + ((size_t)(b*HH + y)*WW)*64;
  const u16* Rrow = phiR + ((size_t)(b*HH + y)*WW)*64;

  // stage Lt: 512 chunks, q = x*8 + j, pre-swizzled source (rule 21)
  #pragma unroll
  for (int c0=0; c0<2; ++c0){
    int q = c0*256 + tid;
    int x = q>>3, j = q&7;
    const u16* g = Lrow + (((size_t)(x0 + x))<<6) + ((j ^ (x&7))<<3);
    gload_lds16(g, &Lt[(q & ~63)*8]);
  }
  // stage Rt: 1536 chunks, col jr <-> gx = x0-128+jr
  #pragma unroll
  for (int c0=0; c0<6; ++c0){
    int q = c0*256 + tid;
    int jr = q>>3, j = q&7;
    int gx = x0 - 128 + jr;
    const u16* g = (gx >= 0) ? (Rrow + (((size_t)gx)<<6) + ((j ^ (jr&7))<<3))
                             : (zpad + (j<<3));
    gload_lds16(g, &Rt[(q & ~63)*8]);
  }
  __syncthreads();

  const int lane = tid & 63;
  const int wv   = tid >> 6;        // wave owns G cols [wv*48, wv*48+48)
  const int l15  = lane & 15;
  const int lh   = lane >> 4;
  const int xorS = (l15&7)<<4;

  f32x4 acc[4][3];
  #pragma unroll
  for (int mt=0;mt<4;++mt)
    #pragma unroll
    for (int nt=0;nt<3;++nt) acc[mt][nt] = (f32x4){0.f,0.f,0.f,0.f};

  const char* tbL = (const char*)Lt;
  const char* tbR = (const char*)Rt;
  #pragma unroll
  for (int kh=0; kh<2; ++kh){
    const int kbyte = kh*64 + lh*16;
    short8 a[4], bb[3];
    #pragma unroll
    for (int mt=0; mt<4; ++mt)
      a[mt] = *(const short8*)(tbL + (mt*16 + l15)*128 + (kbyte ^ xorS));
    #pragma unroll
    for (int nt=0; nt<3; ++nt)
      bb[nt] = *(const short8*)(tbR + (wv*48 + nt*16 + l15)*128 + (kbyte ^ xorS));
    #pragma unroll
    for (int mt=0; mt<4; ++mt)
      #pragma unroll
      for (int nt=0; nt<3; ++nt)
        acc[mt][nt] = __builtin_amdgcn_mfma_f32_16x16x32_bf16(a[mt], bb[nt], acc[mt][nt], 0,0,0);
  }
  __syncthreads();   // everyone done reading Lt/Rt

  // scatter diagonal band: x = D-row, jr = D-col, d = x - jr + 128
  #pragma unroll
  for (int mt=0; mt<4; ++mt){
    #pragma unroll
    for (int nt=0; nt<3; ++nt){
      int jr = wv*48 + nt*16 + l15;
      #pragma unroll
      for (int r=0; r<4; ++r){
        int x = mt*16 + lh*4 + r;
        int d = x - jr + 128;
        if ((unsigned)d < 128u) band[d*65 + x] = acc[mt][nt][r];
      }
    }
  }
  __syncthreads();

  // write out: 2048 float4 chunks (128 d-rows x 16), 256B contiguous per d-row
  float* ob = out + ((size_t)(b*128)*HH + (size_t)y)*WW + x0;
  #pragma unroll
  for (int it=0; it<8; ++it){
    int c = it*256 + tid;
    int d = c>>4, xq = c&15;
    const float* bp = &band[d*65 + xq*4];
    float4 v = make_float4(bp[0], bp[1], bp[2], bp[3]);
    *(float4*)&ob[(size_t)d*HH*WW + xq*4] = v;
  }
}

extern "C" void kernel_launch(void* const* d_in, const int* in_sizes, int n_in,
                              void* d_out, int out_size, void* d_ws, size_t ws_size,
                              hipStream_t stream){
  const float* l  = (const float*)d_in[0];
  const float* r  = (const float*)d_in[1];
  const float* W0 = (const float*)d_in[2];
  const float* b0 = (const float*)d_in[3];
  const float* W1 = (const float*)d_in[4];
  const float* b1 = (const float*)d_in[5];
  const float* W2 = (const float*)d_in[6];
  const float* b2 = (const float*)d_in[7];
  const float* W3 = (const float*)d_in[8];
  const float* b3 = (const float*)d_in[9];
  float* out = (float*)d_out;

  const size_t SIDE = (size_t)2*HH*WW*64;            // elements per side (NHWC bf16)
  u16* wf   = (u16*)d_ws;                            // 110592 u16
  u16* zpad = (u16*)((char*)d_ws + (1u<<20));        // 256 B zeros
  u16* BL   = (u16*)((char*)d_ws + (2u<<20));
  u16* BR   = BL + SIDE;
  u16* A    = (u16*)d_out;                           // ping scratch inside d_out

  hipMemsetAsync(zpad, 0, 256, stream);
  prep_weights<<<dim3(432), dim3(256), 0, stream>>>(W1, W2, W3, wf);

  for (int s = 0; s < 2; ++s){
    const float* img = s ? r : l;
    u16* B = s ? BR : BL;
    conv0_kernel<<<dim3(WW/256, HH, 2), dim3(256), 0, stream>>>(img, W0, b0, A);
    conv64_kernel<true ><<<dim3(WW/64, HH/4, 2), dim3(256), 0, stream>>>(A, wf + 0*36864, b1, zpad, B);
    conv64_kernel<true ><<<dim3(WW/64, HH/4, 2), dim3(256), 0, stream>>>(B, wf + 1*36864, b2, zpad, A);
    conv64_kernel<false><<<dim3(WW/64, HH/4, 2), dim3(256), 0, stream>>>(A, wf + 2*36864, b3, zpad, B);
  }

  corr_kernel<<<dim3(WW/64, HH, 2), dim3(256), 0, stream>>>(BL, BR, zpad, out);
}